// Round 4
// baseline (276.706 us; speedup 1.0000x reference)
//
#include <hip/hip_runtime.h>

// NODEModel MFMA fp16, R12: zero-barrier wave-independent kernel.
// R10/R11 post-mortem: adding waves/SIMD regressed twice -> SIMDs are
// issue-busy (~25 MFMA + ~63 VALU), the idle is the 52x per-block
// {vmcnt(0)+s_barrier} stage drain, which exists only because 4 waves share
// the LDS weight ring. H was ALREADY wave-private in R9.
// R12: weights stream L2->registers per wave (8x global dwordx4 per slab,
// software-pipelined one slab ahead, 13-slab loop fully unrolled so the
// cur<-next rotation is SSA). No lds_w, no s_barrier, no manual waitcnt
// anywhere in node_main. Wave owns 32 samples: acc[8][2]=64 AGPR,
// A cur+nxt = 64 VGPR -> ~200 regs, launch_bounds(256,2) -> 2 waves/SIMD,
// 8 fully independent waves/CU. H = wave-private 8KB slice of 32KB block
// LDS (XOR swizzle unchanged from verified R9). Output: 2 lanes/sample
// half-dot + shfl_xor(32) (verified in R10).
// Risk watched: aggregate L2 weight traffic ~3.4GB/dispatch (~20 TB/s of
// 34.5 ceiling). Fallback if L2-bound: fuse the 3 dp GL-node chains.

#define NTHREADS 256
#define MLP_STRIDE 53248   // fp16 elems per MLP: 4096 WinA + 3*16384 Wh = 13 slabs
#define WINA_ELEMS 4096
#define SLAB_F16 4096      // 8 KB slab
#define TANH_SCALE 2.8853900817779268f   // 2*log2(e)

typedef _Float16 f16;
typedef f16 f16x8 __attribute__((ext_vector_type(8)));
typedef __fp16 fp16x2 __attribute__((ext_vector_type(2)));
typedef float f32x4 __attribute__((ext_vector_type(4)));

// ---------------- prep: fp32 weights -> fp16 fragment-linear (pre-scaled) ----
__global__ __launch_bounds__(NTHREADS)
void prep_kernel(const float* __restrict__ dp_Win, const float* __restrict__ dp_bin,
                 const float* __restrict__ dp_Wh,  const float* __restrict__ dp_bh,
                 const float* __restrict__ ic_Win, const float* __restrict__ ic_bin,
                 const float* __restrict__ ic_Wh,  const float* __restrict__ ic_bh,
                 f16* __restrict__ wsw)
{
    int e = blockIdx.x * NTHREADS + threadIdx.x;
    if (e >= 2 * MLP_STRIDE + 768) return;
    if (e >= 2 * MLP_STRIDE) {          // scaled hidden biases, fp32
        int idx = e - 2 * MLP_STRIDE;   // [mlp(2)][l(3)][m(128)]
        int mlp = idx / 384, rem = idx % 384;
        const float* bh = mlp ? ic_bh : dp_bh;
        float* bsc = (float*)(wsw + 2 * MLP_STRIDE);
        bsc[idx] = bh[rem] * TANH_SCALE;
        return;
    }
    int mlp = (e >= MLP_STRIDE) ? 1 : 0;   // 0 = dp, 1 = ic
    int r = e - mlp * MLP_STRIDE;
    const float* Win = mlp ? ic_Win : dp_Win;
    const float* bin = mlp ? ic_bin : dp_bin;
    const float* Wh  = mlp ? ic_Wh  : dp_Wh;
    int din = mlp ? 5 : 6;
    float val;
    if (r < WINA_ELEMS) {
        int mt = r >> 9, lane = (r >> 3) & 63, j = r & 7;
        int m = mt * 16 + (lane & 15);
        int k = ((lane >> 4) << 3) + j;                     // 0..31
        val = (k < din) ? Win[k * 128 + m] : ((k == din) ? bin[m] : 0.0f);
    } else {
        int r2 = r - WINA_ELEMS;
        int l = r2 >> 14, r3 = r2 & 16383;
        int ks = r3 >> 12, mt = (r3 >> 9) & 7, lane = (r3 >> 3) & 63, j = r3 & 7;
        int m = mt * 16 + (lane & 15);
        int k = ks * 32 + ((lane >> 4) << 3) + j;           // 0..127
        val = Wh[(l * 128 + k) * 128 + m];
    }
    wsw[e] = (f16)(val * TANH_SCALE);
}

// ---------------- main ----------------
__device__ __forceinline__ float tanh_fast(float x) {
    // input pre-scaled by 2*log2e: tanh = 1 - 2/(exp2(x)+1)
    float e = __builtin_amdgcn_exp2f(x);
    float r = __builtin_amdgcn_rcpf(e + 1.0f);
    return fmaf(-2.0f, r, 1.0f);
}

__device__ __forceinline__ unsigned int pk16(float a, float b) {
    union { fp16x2 h; unsigned int u; } c;
    c.h = __builtin_amdgcn_cvt_pkrtz(a, b);
    return c.u;
}

__device__ __forceinline__ int h_addr(int n, int kb) {
    return n * 256 + ((((kb >> 4) ^ (n & 7)) << 4) | (kb & 15));
}

__device__ __forceinline__ f32x4 mfma16(f16x8 a, f16x8 b, f32x4 c) {
    return __builtin_amdgcn_mfma_f32_16x16x32_f16(a, b, c, 0, 0, 0);
}

__global__ __launch_bounds__(NTHREADS, 2)
void node_main(const float* __restrict__ tx, const f16* __restrict__ wsw,
               const float* __restrict__ dp_Wout, const float* __restrict__ dp_bout,
               const float* __restrict__ ic_Wout, const float* __restrict__ ic_bout,
               float* __restrict__ out)
{
    __shared__ __align__(16) unsigned char lds_h[32768];   // 4 waves x 32 smp x 256 B, wave-private slices

    const int tid  = threadIdx.x;
    const int lane = tid & 63;
    const int wv   = tid >> 6;           // 0..3
    const int q    = lane >> 4;
    const int l15  = lane & 15;
    const int p0   = blockIdx.x * 128;
    const int n0   = wv * 32 + l15;      // sample of nt=0 B-frag col (wave-private range)
    const int hb0  = n0 * 256;

    // ---- precomputed, chain/layer-invariant LDS addresses (nt via +4096*nt) --
    const int d   = l15 & 7;
    const int e2  = q >> 1;
    const int par = (q & 1) << 3;
    int waddr[8];
    #pragma unroll
    for (int mt = 0; mt < 8; ++mt)
        waddr[mt] = hb0 + ((((2 * mt + e2) ^ d) << 4) | par);
    int raddr[4];
    #pragma unroll
    for (int ks = 0; ks < 4; ++ks)
        raddr[ks] = hb0 + (((4 * ks + q) ^ d) << 4);

    const float* bsc = (const float*)(wsw + 2 * MLP_STRIDE);

    const float4* tx4 = (const float4*)tx;

    // features for the 2 B-frag sample groups (meaningful in lanes 0..15)
    float rA[2], xA[2], yA[2], zA[2], iA[2], aA[2];
    #pragma unroll
    for (int nt = 0; nt < 2; ++nt) {
        float4 tv = tx4[p0 + n0 + 16 * nt];
        float xx = tv.y, yy = tv.z, zz = tv.w;
        float rr = sqrtf(fmaf(xx, xx, fmaf(yy, yy, zz * zz)));
        float irs = 1.0f / fmaxf(rr, 1e-8f);
        rA[nt] = rr; xA[nt] = xx * irs; yA[nt] = yy * irs; zA[nt] = zz * irs;
        iA[nt] = 1.0f / (1.0f + rr);
        aA[nt] = 0.5f * tv.x;
    }
    // own sample (output layer): 2 lanes per sample, halves hi=0/1
    const int sown = wv * 32 + (lane & 31);
    const int hi   = lane >> 5;
    float ao, io;
    {
        float4 tv = tx4[p0 + sown];
        float xx = tv.y, yy = tv.z, zz = tv.w;
        float rr = sqrtf(fmaf(xx, xx, fmaf(yy, yy, zz * zz)));
        io = 1.0f / (1.0f + rr);
        ao = 0.5f * tv.x;
    }

    const f32x4 z4 = {0.f, 0.f, 0.f, 0.f};
    float icv = 0.0f, dsum = 0.0f;

    // A-fragment registers: current slab, loaded one slab ahead.
    f16x8 aC[8];
    {
        const f16x8* gp = (const f16x8*)(wsw + MLP_STRIDE);   // chain 0 (ic), slab 0
        #pragma unroll
        for (int mt = 0; mt < 8; ++mt)
            aC[mt] = gp[mt * 64 + lane];
    }

    #pragma unroll 1
    for (int c = 0; c < 4; ++c) {
        const f16* wb       = wsw + (c == 0 ? MLP_STRIDE : 0);
        const float* bb     = bsc + (c == 0 ? 384 : 0);
        const float* Wout   = (c == 0) ? ic_Wout : dp_Wout;
        const float* bout   = (c == 0) ? ic_bout : dp_bout;
        const float tn = (c == 1) ? 0.22540333075851662f
                       : ((c == 2) ? 1.0f : 1.7745966692414834f);   // node+1

        // ---- B frags for the input layer (lanes 0..15 hold real data) ----
        f16x8 bfr[2];
        #pragma unroll
        for (int nt = 0; nt < 2; ++nt) {
            f16x8 b = {};
            if (lane < 16) {
                if (c == 0) {
                    b[0] = (f16)rA[nt]; b[1] = (f16)xA[nt]; b[2] = (f16)yA[nt];
                    b[3] = (f16)zA[nt]; b[4] = (f16)iA[nt]; b[5] = (f16)1.0f;
                } else {
                    b[0] = (f16)(aA[nt] * tn); b[1] = (f16)rA[nt]; b[2] = (f16)xA[nt];
                    b[3] = (f16)yA[nt]; b[4] = (f16)zA[nt]; b[5] = (f16)iA[nt];
                    b[6] = (f16)1.0f;
                }
            }
            bfr[nt] = b;
        }

        f32x4 acc[8][2];

        #pragma unroll
        for (int sw = 0; sw < 13; ++sw) {
            // ---- issue next slab's A loads (L2-resident weights) ----
            // sw==12: next chain's slab 0 = dp base (harmless dead load for c==3)
            f16x8 aN[8];
            {
                const f16x8* gp = (const f16x8*)((sw < 12) ? (wb + (sw + 1) * SLAB_F16)
                                                           : wsw);
                #pragma unroll
                for (int mt = 0; mt < 8; ++mt)
                    aN[mt] = gp[mt * 64 + lane];
            }

            if (sw == 0) {
                // ---- input layer: 8mt x 2nt MFMAs ----
                #pragma unroll
                for (int mt = 0; mt < 8; ++mt) {
                    #pragma unroll
                    for (int nt = 0; nt < 2; ++nt)
                        acc[mt][nt] = mfma16(aC[mt], bfr[nt], z4);
                }
                #pragma unroll
                for (int mt = 0; mt < 8; ++mt) {
                    #pragma unroll
                    for (int nt = 0; nt < 2; ++nt) {
                        f32x4 v = acc[mt][nt];
                        uint2 o;
                        o.x = pk16(tanh_fast(v[0]), tanh_fast(v[1]));
                        o.y = pk16(tanh_fast(v[2]), tanh_fast(v[3]));
                        *(uint2*)(lds_h + waddr[mt] + nt * 4096) = o;
                    }
                }
            } else {
                // ---- hidden layer slab: l = (sw-1)/4, ks = (sw-1)%4 ----
                const int l  = (sw - 1) >> 2;
                const int ks = (sw - 1) & 3;
                f16x8 hb[2];
                #pragma unroll
                for (int nt = 0; nt < 2; ++nt)
                    hb[nt] = *(const f16x8*)(lds_h + raddr[ks] + nt * 4096);
                if (ks == 0) {
                    const float* bl = bb + l * 128;
                    #pragma unroll
                    for (int mt = 0; mt < 8; ++mt) {
                        f32x4 b4 = *(const f32x4*)(bl + mt * 16 + q * 4);
                        #pragma unroll
                        for (int nt = 0; nt < 2; ++nt)
                            acc[mt][nt] = mfma16(aC[mt], hb[nt], b4);
                    }
                } else {
                    #pragma unroll
                    for (int mt = 0; mt < 8; ++mt) {
                        #pragma unroll
                        for (int nt = 0; nt < 2; ++nt)
                            acc[mt][nt] = mfma16(aC[mt], hb[nt], acc[mt][nt]);
                    }
                }
                if (ks == 3) {
                    #pragma unroll
                    for (int mt = 0; mt < 8; ++mt) {
                        #pragma unroll
                        for (int nt = 0; nt < 2; ++nt) {
                            f32x4 v = acc[mt][nt];
                            uint2 o;
                            o.x = pk16(tanh_fast(v[0]), tanh_fast(v[1]));
                            o.y = pk16(tanh_fast(v[2]), tanh_fast(v[3]));
                            *(uint2*)(lds_h + waddr[mt] + nt * 4096) = o;
                        }
                    }
                }
            }

            // ---- rotate prefetch regs (compile-time, SSA after unroll) ----
            #pragma unroll
            for (int mt = 0; mt < 8; ++mt)
                aC[mt] = aN[mt];
        }

        // ---- output layer: 2 lanes per sample, 64-elem half-dot (wave-private H,
        //      no barrier; compiler orders LDS via lgkmcnt) ----
        {
            float sum = 0.0f;
            #pragma unroll
            for (int u = 0; u < 8; ++u) {
                const int gdx = hi * 8 + u;
                f16x8 hv = *(const f16x8*)(lds_h + h_addr(sown, gdx * 16));
                f32x4 w0 = *(const f32x4*)(Wout + gdx * 8);
                f32x4 w1 = *(const f32x4*)(Wout + gdx * 8 + 4);
                sum = fmaf((float)hv[0], w0[0], sum);
                sum = fmaf((float)hv[1], w0[1], sum);
                sum = fmaf((float)hv[2], w0[2], sum);
                sum = fmaf((float)hv[3], w0[3], sum);
                sum = fmaf((float)hv[4], w1[0], sum);
                sum = fmaf((float)hv[5], w1[1], sum);
                sum = fmaf((float)hv[6], w1[2], sum);
                sum = fmaf((float)hv[7], w1[3], sum);
            }
            sum += __shfl_xor(sum, 32);
            float val = sum + bout[0];
            if (c == 0) icv = val;
            else        dsum = fmaf((c == 2) ? (8.0f / 9.0f) : (5.0f / 9.0f), val, dsum);
        }
    }

    if (lane < 32)
        out[p0 + sown] = (icv + ao * dsum) * io;
}

extern "C" void kernel_launch(void* const* d_in, const int* in_sizes, int n_in,
                              void* d_out, int out_size, void* d_ws, size_t ws_size,
                              hipStream_t stream) {
    const float* tx      = (const float*)d_in[0];
    const float* dp_Win  = (const float*)d_in[1];
    const float* dp_bin  = (const float*)d_in[2];
    const float* dp_Wh   = (const float*)d_in[3];
    const float* dp_bh   = (const float*)d_in[4];
    const float* dp_Wout = (const float*)d_in[5];
    const float* dp_bout = (const float*)d_in[6];
    const float* ic_Win  = (const float*)d_in[7];
    const float* ic_bin  = (const float*)d_in[8];
    const float* ic_Wh   = (const float*)d_in[9];
    const float* ic_bh   = (const float*)d_in[10];
    const float* ic_Wout = (const float*)d_in[11];
    const float* ic_bout = (const float*)d_in[12];
    float* out = (float*)d_out;
    f16* wsw = (f16*)d_ws;

    int n = in_sizes[0] / 4;

    prep_kernel<<<dim3((2 * MLP_STRIDE + 768 + NTHREADS - 1) / NTHREADS), dim3(NTHREADS), 0, stream>>>(
        dp_Win, dp_bin, dp_Wh, dp_bh, ic_Win, ic_bin, ic_Wh, ic_bh, wsw);

    node_main<<<dim3(n / 128), dim3(NTHREADS), 0, stream>>>(
        tx, wsw, dp_Wout, dp_bout, ic_Wout, ic_bout, out);
}

// Round 5
// 244.437 us; speedup vs baseline: 1.1320x; 1.1320x over previous
//
#include <hip/hip_runtime.h>

// NODEModel MFMA fp16, R13: back to R9 skeleton (best, 195.5us) + work removal.
// R10/R11/R12 post-mortems: MfmaUtil*dur conserved across all variants ->
// MFMA work fixed; occupancy-up (x2) and barrier-removal both ADDED idle or
// VALU work. R9 is the unique LDS/reg-feasible point (acc[8][4]=128 AGPR ->
// 2 waves/SIMD; H 64KB + ring 16KB -> 2 blocks/CU) and sits at ~88% combined
// issue. So: remove work. Trans pipe (exp2+rcp, quarter-rate) ~28% of cycles
// = largest non-MFMA term.
// R13a: pairwise-batched reciprocal tanh: one rcp serves TWO activations
// (n2 = -2*rcp(a0*a1); t_i = fma(n2, a_other, 1)). Per 2 acts:
// 4 trans+5 VALU -> 3 trans+7 VALU. Extra rounding ~2^-23, invisible under
// fp16 H storage. R13b: s_setprio(1) around MFMA clusters (SIMD-mate wave is
// an independent block -> attn-like regime where setprio measured +4-7%).
// Everything else byte-identical to R9 (verified layouts, ring pipeline,
// 64-sample waves, scalar output dot).

#define NTHREADS 256
#define MLP_STRIDE 53248   // fp16 elems per MLP: 4096 WinA + 3*16384 Wh = 13 slabs
#define WINA_ELEMS 4096
#define WH_ELEMS 16384
#define SLAB_F16 4096      // 8 KB slab
#define TANH_SCALE 2.8853900817779268f   // 2*log2(e)

typedef _Float16 f16;
typedef f16 f16x8 __attribute__((ext_vector_type(8)));
typedef __fp16 fp16x2 __attribute__((ext_vector_type(2)));
typedef float f32x4 __attribute__((ext_vector_type(4)));

// ---------------- prep: fp32 weights -> fp16 fragment-linear (pre-scaled) ----
__global__ __launch_bounds__(NTHREADS)
void prep_kernel(const float* __restrict__ dp_Win, const float* __restrict__ dp_bin,
                 const float* __restrict__ dp_Wh,  const float* __restrict__ dp_bh,
                 const float* __restrict__ ic_Win, const float* __restrict__ ic_bin,
                 const float* __restrict__ ic_Wh,  const float* __restrict__ ic_bh,
                 f16* __restrict__ wsw)
{
    int e = blockIdx.x * NTHREADS + threadIdx.x;
    if (e >= 2 * MLP_STRIDE + 768) return;
    if (e >= 2 * MLP_STRIDE) {          // scaled hidden biases, fp32
        int idx = e - 2 * MLP_STRIDE;   // [mlp(2)][l(3)][m(128)]
        int mlp = idx / 384, rem = idx % 384;
        const float* bh = mlp ? ic_bh : dp_bh;
        float* bsc = (float*)(wsw + 2 * MLP_STRIDE);
        bsc[idx] = bh[rem] * TANH_SCALE;
        return;
    }
    int mlp = (e >= MLP_STRIDE) ? 1 : 0;   // 0 = dp, 1 = ic
    int r = e - mlp * MLP_STRIDE;
    const float* Win = mlp ? ic_Win : dp_Win;
    const float* bin = mlp ? ic_bin : dp_bin;
    const float* Wh  = mlp ? ic_Wh  : dp_Wh;
    int din = mlp ? 5 : 6;
    float val;
    if (r < WINA_ELEMS) {
        int mt = r >> 9, lane = (r >> 3) & 63, j = r & 7;
        int m = mt * 16 + (lane & 15);
        int k = ((lane >> 4) << 3) + j;                     // 0..31
        val = (k < din) ? Win[k * 128 + m] : ((k == din) ? bin[m] : 0.0f);
    } else {
        int r2 = r - WINA_ELEMS;
        int l = r2 >> 14, r3 = r2 & 16383;
        int ks = r3 >> 12, mt = (r3 >> 9) & 7, lane = (r3 >> 3) & 63, j = r3 & 7;
        int m = mt * 16 + (lane & 15);
        int k = ks * 32 + ((lane >> 4) << 3) + j;           // 0..127
        val = Wh[(l * 128 + k) * 128 + m];
    }
    wsw[e] = (f16)(val * TANH_SCALE);
}

// ---------------- main ----------------
__device__ __forceinline__ unsigned int tanh2_pk(float x0, float x1) {
    // inputs pre-scaled by 2*log2e: tanh = 1 - 2/(exp2(x)+1).
    // Batched reciprocal: one rcp serves both lanes' pair.
    float a0 = __builtin_amdgcn_exp2f(x0) + 1.0f;
    float a1 = __builtin_amdgcn_exp2f(x1) + 1.0f;
    float n2 = -2.0f * __builtin_amdgcn_rcpf(a0 * a1);
    union { fp16x2 h; unsigned int u; } c;
    c.h = __builtin_amdgcn_cvt_pkrtz(fmaf(n2, a1, 1.0f), fmaf(n2, a0, 1.0f));
    return c.u;
}

__device__ __forceinline__ int h_addr(int n, int kb) {
    return n * 256 + ((((kb >> 4) ^ (n & 7)) << 4) | (kb & 15));
}

__device__ __forceinline__ f32x4 mfma16(f16x8 a, f16x8 b, f32x4 c) {
    return __builtin_amdgcn_mfma_f32_16x16x32_f16(a, b, c, 0, 0, 0);
}

__device__ __forceinline__ void stage16(const void* g, void* l) {
    __builtin_amdgcn_global_load_lds((const __attribute__((address_space(1))) void*)g,
                                     (__attribute__((address_space(3))) void*)l, 16, 0, 0);
}

#define WAITCNT_VM0_LGKM0 0x0070   // vmcnt=0, expcnt=7 (dc), lgkmcnt=0

__global__ __launch_bounds__(NTHREADS, 2)
void node_main(const float* __restrict__ tx, const f16* __restrict__ wsw,
               const float* __restrict__ dp_Wout, const float* __restrict__ dp_bout,
               const float* __restrict__ ic_Wout, const float* __restrict__ ic_bout,
               float* __restrict__ out)
{
    __shared__ __align__(16) unsigned char lds_h[65536];     // 4 waves x 64 samples x 256 B
    __shared__ __align__(16) unsigned char lds_w[2][8192];   // ring

    const int tid  = threadIdx.x;
    const int lane = tid & 63;
    const int wv   = tid >> 6;
    const int q    = lane >> 4;
    const int l15  = lane & 15;
    const int p0   = blockIdx.x * 256;
    const int n0   = wv * 64 + l15;      // sample of nt=0 B-frag col

    // ---- precomputed, chain/layer-invariant LDS addresses (nt via +4096*nt) --
    const int d   = l15 & 7;
    const int e2  = q >> 1;
    const int par = (q & 1) << 3;
    int waddr[8];
    #pragma unroll
    for (int mt = 0; mt < 8; ++mt)
        waddr[mt] = n0 * 256 + ((((2 * mt + e2) ^ d) << 4) | par);
    int raddr[4];
    #pragma unroll
    for (int ks = 0; ks < 4; ++ks)
        raddr[ks] = n0 * 256 + (((4 * ks + q) ^ d) << 4);

    const float* bsc = (const float*)(wsw + 2 * MLP_STRIDE);

    const float4* tx4 = (const float4*)tx;

    // features for the 4 B-frag sample groups (meaningful in lanes 0..15)
    float rA[4], xA[4], yA[4], zA[4], iA[4], aA[4];
    #pragma unroll
    for (int nt = 0; nt < 4; ++nt) {
        float4 tv = tx4[p0 + n0 + 16 * nt];
        float xx = tv.y, yy = tv.z, zz = tv.w;
        float rr = sqrtf(fmaf(xx, xx, fmaf(yy, yy, zz * zz)));
        float irs = 1.0f / fmaxf(rr, 1e-8f);
        rA[nt] = rr; xA[nt] = xx * irs; yA[nt] = yy * irs; zA[nt] = zz * irs;
        iA[nt] = 1.0f / (1.0f + rr);
        aA[nt] = 0.5f * tv.x;
    }
    // own sample (for output layer / combine): 1 sample per lane, no shuffle
    const int sown = wv * 64 + lane;
    float ao, io;
    {
        float4 tv = tx4[p0 + sown];
        float xx = tv.y, yy = tv.z, zz = tv.w;
        float rr = sqrtf(fmaf(xx, xx, fmaf(yy, yy, zz * zz)));
        io = 1.0f / (1.0f + rr);
        ao = 0.5f * tv.x;
    }

    const f32x4 z4 = {0.f, 0.f, 0.f, 0.f};
    float icv = 0.0f, dsum = 0.0f;
    int p = 0;

    // prologue: stage slab 0 of chain 0 (ic WinA) into slot 0
    {
        const char* g = (const char*)(wsw + MLP_STRIDE);
        stage16(g + tid * 16, &lds_w[0][0] + tid * 16);
        stage16(g + 4096 + tid * 16, &lds_w[0][0] + 4096 + tid * 16);
    }

    for (int c = 0; c < 4; ++c) {
        const f16* wb       = wsw + (c == 0 ? MLP_STRIDE : 0);
        const float* bb     = bsc + (c == 0 ? 384 : 0);
        const float* Wout   = (c == 0) ? ic_Wout : dp_Wout;
        const float* bout   = (c == 0) ? ic_bout : dp_bout;
        const float tn = (c == 1) ? 0.22540333075851662f
                       : ((c == 2) ? 1.0f : 1.7745966692414834f);   // node+1

        // ---- B frags for the input layer (lanes 0..15 hold real data) ----
        f16x8 bfr[4];
        #pragma unroll
        for (int nt = 0; nt < 4; ++nt) {
            f16x8 b = {};
            if (lane < 16) {
                if (c == 0) {
                    b[0] = (f16)rA[nt]; b[1] = (f16)xA[nt]; b[2] = (f16)yA[nt];
                    b[3] = (f16)zA[nt]; b[4] = (f16)iA[nt]; b[5] = (f16)1.0f;
                } else {
                    b[0] = (f16)(aA[nt] * tn); b[1] = (f16)rA[nt]; b[2] = (f16)xA[nt];
                    b[3] = (f16)yA[nt]; b[4] = (f16)zA[nt]; b[5] = (f16)iA[nt];
                    b[6] = (f16)1.0f;
                }
            }
            bfr[nt] = b;
        }

        f32x4 acc[8][4];

        #pragma unroll 1
        for (int sw = 0; sw < 13; ++sw) {
            // ---- pipelined sync point ----
            __asm__ __volatile__("" ::: "memory");
            __builtin_amdgcn_s_waitcnt(WAITCNT_VM0_LGKM0);
            __builtin_amdgcn_s_barrier();
            __asm__ __volatile__("" ::: "memory");

            // ---- issue next slab's stage into the other slot ----
            if (!(c == 3 && sw == 12)) {
                const char* g = (sw < 12) ? (const char*)(wb + (sw + 1) * SLAB_F16)
                                          : (const char*)wsw;   // next chain = dp base
                unsigned char* dst = &lds_w[p ^ 1][0];
                stage16(g + tid * 16, dst + tid * 16);
                stage16(g + 4096 + tid * 16, dst + 4096 + tid * 16);
            }
            __asm__ __volatile__("" ::: "memory");

            const unsigned char* A = &lds_w[p][0];

            if (sw == 0) {
                // ---- input layer: 8mt x 4nt MFMAs ----
                __builtin_amdgcn_s_setprio(1);
                #pragma unroll
                for (int mt = 0; mt < 8; ++mt) {
                    f16x8 a = *(const f16x8*)(A + ((mt * 64 + lane) << 4));
                    #pragma unroll
                    for (int nt = 0; nt < 4; ++nt)
                        acc[mt][nt] = mfma16(a, bfr[nt], z4);
                }
                __builtin_amdgcn_s_setprio(0);
                #pragma unroll
                for (int mt = 0; mt < 8; ++mt) {
                    #pragma unroll
                    for (int nt = 0; nt < 4; ++nt) {
                        f32x4 v = acc[mt][nt];
                        uint2 o;
                        o.x = tanh2_pk(v[0], v[1]);
                        o.y = tanh2_pk(v[2], v[3]);
                        *(uint2*)(lds_h + waddr[mt] + nt * 4096) = o;
                    }
                }
            } else {
                // ---- hidden layer slab: l = (sw-1)/4, ks = (sw-1)%4 ----
                int l  = (sw - 1) >> 2;
                int ks = (sw - 1) & 3;
                f16x8 hb[4];
                #pragma unroll
                for (int nt = 0; nt < 4; ++nt)
                    hb[nt] = *(const f16x8*)(lds_h + raddr[ks] + nt * 4096);
                if (ks == 0) {
                    const float* bl = bb + l * 128;
                    __builtin_amdgcn_s_setprio(1);
                    #pragma unroll
                    for (int mt = 0; mt < 8; ++mt) {
                        f16x8 a = *(const f16x8*)(A + ((mt * 64 + lane) << 4));
                        f32x4 b4 = *(const f32x4*)(bl + mt * 16 + q * 4);
                        #pragma unroll
                        for (int nt = 0; nt < 4; ++nt)
                            acc[mt][nt] = mfma16(a, hb[nt], b4);
                    }
                    __builtin_amdgcn_s_setprio(0);
                } else {
                    __builtin_amdgcn_s_setprio(1);
                    #pragma unroll
                    for (int mt = 0; mt < 8; ++mt) {
                        f16x8 a = *(const f16x8*)(A + ((mt * 64 + lane) << 4));
                        #pragma unroll
                        for (int nt = 0; nt < 4; ++nt)
                            acc[mt][nt] = mfma16(a, hb[nt], acc[mt][nt]);
                    }
                    __builtin_amdgcn_s_setprio(0);
                }
                if (ks == 3) {
                    #pragma unroll
                    for (int mt = 0; mt < 8; ++mt) {
                        #pragma unroll
                        for (int nt = 0; nt < 4; ++nt) {
                            f32x4 v = acc[mt][nt];
                            uint2 o;
                            o.x = tanh2_pk(v[0], v[1]);
                            o.y = tanh2_pk(v[2], v[3]);
                            *(uint2*)(lds_h + waddr[mt] + nt * 4096) = o;
                        }
                    }
                }
            }
            p ^= 1;
        }

        // ---- output layer: 1 sample per lane, 128-elem dot from own H ----
        {
            float sum = 0.0f;
            #pragma unroll
            for (int u = 0; u < 16; ++u) {
                f16x8 hv = *(const f16x8*)(lds_h + h_addr(sown, u * 16));
                f32x4 w0 = *(const f32x4*)(Wout + u * 8);
                f32x4 w1 = *(const f32x4*)(Wout + u * 8 + 4);
                sum = fmaf((float)hv[0], w0[0], sum);
                sum = fmaf((float)hv[1], w0[1], sum);
                sum = fmaf((float)hv[2], w0[2], sum);
                sum = fmaf((float)hv[3], w0[3], sum);
                sum = fmaf((float)hv[4], w1[0], sum);
                sum = fmaf((float)hv[5], w1[1], sum);
                sum = fmaf((float)hv[6], w1[2], sum);
                sum = fmaf((float)hv[7], w1[3], sum);
            }
            float val = sum + bout[0];
            if (c == 0) icv = val;
            else        dsum = fmaf((c == 2) ? (8.0f / 9.0f) : (5.0f / 9.0f), val, dsum);
        }
    }

    out[p0 + sown] = (icv + ao * dsum) * io;

}

extern "C" void kernel_launch(void* const* d_in, const int* in_sizes, int n_in,
                              void* d_out, int out_size, void* d_ws, size_t ws_size,
                              hipStream_t stream) {
    const float* tx      = (const float*)d_in[0];
    const float* dp_Win  = (const float*)d_in[1];
    const float* dp_bin  = (const float*)d_in[2];
    const float* dp_Wh   = (const float*)d_in[3];
    const float* dp_bh   = (const float*)d_in[4];
    const float* dp_Wout = (const float*)d_in[5];
    const float* dp_bout = (const float*)d_in[6];
    const float* ic_Win  = (const float*)d_in[7];
    const float* ic_bin  = (const float*)d_in[8];
    const float* ic_Wh   = (const float*)d_in[9];
    const float* ic_bh   = (const float*)d_in[10];
    const float* ic_Wout = (const float*)d_in[11];
    const float* ic_bout = (const float*)d_in[12];
    float* out = (float*)d_out;
    f16* wsw = (f16*)d_ws;

    int n = in_sizes[0] / 4;

    prep_kernel<<<dim3((2 * MLP_STRIDE + 768 + NTHREADS - 1) / NTHREADS), dim3(NTHREADS), 0, stream>>>(
        dp_Win, dp_bin, dp_Wh, dp_bh, ic_Win, ic_bin, ic_Wh, ic_bh, wsw);

    node_main<<<dim3(n / 256), dim3(NTHREADS), 0, stream>>>(
        tx, wsw, dp_Wout, dp_bout, ic_Wout, ic_bout, out);
}